// Round 7
// baseline (619.829 us; speedup 1.0000x reference)
//
#include <hip/hip_runtime.h>

// Problem constants (fixed by the reference)
#define NB    2
#define LQT   12096      // query tokens per batch
#define LINT  2304       // feat tokens per batch (48*48)
#define DIMC  768
#define NHD   6
#define NPT   4
#define DHD   128
#define HIDC  192
#define HH    48
#define WW    48

typedef __attribute__((ext_vector_type(8))) short bf16x8;
typedef __attribute__((ext_vector_type(4))) float f32x4;

__device__ __forceinline__ unsigned short f2bf(float f) {
  unsigned int u = __builtin_bit_cast(unsigned int, f);
  u += 0x7FFFu + ((u >> 16) & 1u);   // round-to-nearest-even
  return (unsigned short)(u >> 16);
}
__device__ __forceinline__ float bf2f(unsigned short h) {
  unsigned int u = ((unsigned int)h) << 16;
  return __builtin_bit_cast(float, u);
}

// global -> LDS direct copy, 16B per lane. LDS base must be wave-uniform.
__device__ __forceinline__ void gload16(const unsigned short* g, unsigned short* l) {
  __builtin_amdgcn_global_load_lds(
      (const __attribute__((address_space(1))) unsigned int*)g,
      (__attribute__((address_space(3))) unsigned int*)l, 16, 0, 0);
}

template <int N> __device__ __forceinline__ void wait_vm() {
  if constexpr (N == 0)      asm volatile("s_waitcnt vmcnt(0)" ::: "memory");
  else if constexpr (N == 6) asm volatile("s_waitcnt vmcnt(6)" ::: "memory");
  else if constexpr (N == 12) asm volatile("s_waitcnt vmcnt(12)" ::: "memory");
}

// ---------------- weight packing: transpose [K][N]->bf16 [rows>=N][K], pad rows with 0
__global__ __launch_bounds__(256) void pack_wt(const float* __restrict__ src,
                                               unsigned short* __restrict__ dst,
                                               int K, int N, int rows) {
  size_t i = (size_t)blockIdx.x * 256 + threadIdx.x;
  if (i >= (size_t)rows * K) return;
  int n = (int)(i / K), k = (int)(i % K);
  float v = (n < N) ? src[(size_t)k * N + n] : 0.f;
  dst[i] = f2bf(v);
}

// fused sampling-offset (48 cols) + attn-weight (24 cols) weight pack into [128][768]
__global__ __launch_bounds__(256) void pack_soaw(const float* __restrict__ soW,
                                                 const float* __restrict__ awW,
                                                 const float* __restrict__ sob,
                                                 const float* __restrict__ awb,
                                                 unsigned short* __restrict__ dst,
                                                 float* __restrict__ bdst) {
  size_t i = (size_t)blockIdx.x * 256 + threadIdx.x;
  if (i < 128) bdst[i] = (i < 48) ? sob[i] : (i < 72 ? awb[i - 48] : 0.f);
  if (i >= (size_t)128 * DIMC) return;
  int n = (int)(i / DIMC), k = (int)(i % DIMC);
  float v = (n < 48) ? soW[(size_t)k * 48 + n]
                     : (n < 72 ? awW[(size_t)k * 24 + (n - 48)] : 0.f);
  dst[i] = f2bf(v);
}

// ---------------- LayerNorm (eps=1e-6), templated input dtype, -> bf16
template <bool IN_BF16>
__global__ __launch_bounds__(256) void ln_to_bf16(const void* __restrict__ in_,
                                                  const float* __restrict__ gamma,
                                                  const float* __restrict__ beta,
                                                  unsigned short* __restrict__ out) {
  const int row = blockIdx.x;
  const int t = threadIdx.x;
  float v0, v1, v2;
  if (IN_BF16) {
    const unsigned short* x = (const unsigned short*)in_ + (size_t)row * DIMC;
    v0 = bf2f(x[t]); v1 = bf2f(x[t + 256]); v2 = bf2f(x[t + 512]);
  } else {
    const float* x = (const float*)in_ + (size_t)row * DIMC;
    v0 = x[t]; v1 = x[t + 256]; v2 = x[t + 512];
  }
  float s = v0 + v1 + v2;
  float s2 = v0 * v0 + v1 * v1 + v2 * v2;
#pragma unroll
  for (int o = 32; o > 0; o >>= 1) {
    s += __shfl_down(s, o);
    s2 += __shfl_down(s2, o);
  }
  __shared__ float red[8];
  const int wave = t >> 6, lane = t & 63;
  if (lane == 0) { red[wave] = s; red[wave + 4] = s2; }
  __syncthreads();
  float S = red[0] + red[1] + red[2] + red[3];
  float S2 = red[4] + red[5] + red[6] + red[7];
  float mean = S * (1.0f / DIMC);
  float var = S2 * (1.0f / DIMC) - mean * mean;
  float inv = rsqrtf(var + 1e-6f);
  unsigned short* o0 = out + (size_t)row * DIMC;
  o0[t]       = f2bf((v0 - mean) * inv * gamma[t]       + beta[t]);
  o0[t + 256] = f2bf((v1 - mean) * inv * gamma[t + 256] + beta[t + 256]);
  o0[t + 512] = f2bf((v2 - mean) * inv * gamma[t + 512] + beta[t + 512]);
}

// ---------------- LDS-pipelined MFMA GEMM (kept for v-proj: M small, K=N=768)
template <int WM, int WN, bool HAS_ADD, bool ADD_BF16, bool OUT_BF16>
__global__ __launch_bounds__(256) void gemm_bt(const unsigned short* __restrict__ A,
                                               const unsigned short* __restrict__ Bt,
                                               const float* __restrict__ bias,
                                               const void* __restrict__ add_,
                                               void* __restrict__ out_,
                                               int M, int N, int K, int nn) {
  constexpr int BM = 2 * WM * 16;
  constexpr int BN = 2 * WN * 16;
  constexpr int LPS = (BM + BN) / 64;
  constexpr int CA = BM * 4;
  __shared__ unsigned short As[3][BM * 32];
  __shared__ unsigned short Bs[3][BN * 32];
  const int t = threadIdx.x;
  const int wave = t >> 6, lane = t & 63;

  const int nwg = gridDim.x;
  const int qq = nwg >> 3, rr = nwg & 7;
  const int xcd = blockIdx.x & 7, pos = blockIdx.x >> 3;
  const int swz = ((xcd < rr) ? xcd * (qq + 1) : rr * (qq + 1) + (xcd - rr) * qq) + pos;
  const int m0 = (swz / nn) * BM;
  const int n0 = (swz % nn) * BN;

  const int wm = (wave >> 1) * (WM * 16), wn = (wave & 1) * (WN * 16);
  const int lr = lane & 15;
  const int lg = lane >> 4;

  auto stage = [&](int buf, int k0) {
#pragma unroll
    for (int i = 0; i < LPS; ++i) {
      const int c = t + i * 256;
      if (c < CA) {
        const int row = c >> 2, slot = c & 3;
        const int ca = slot ^ ((row >> 1) & 3);
        gload16(A + (size_t)(m0 + row) * K + k0 + ca * 8, &As[buf][c * 8]);
      } else {
        const int c2 = c - CA, row = c2 >> 2, slot = c2 & 3;
        const int ca = slot ^ ((row >> 1) & 3);
        gload16(Bt + (size_t)(n0 + row) * K + k0 + ca * 8, &Bs[buf][c2 * 8]);
      }
    }
  };

  f32x4 acc[WM][WN] = {};
  const int NT = K >> 5;

  stage(0, 0);
  stage(1, 32);
  stage(2, 64);

  int buf = 0;
  for (int kt = 0; kt < NT; ++kt) {
    if (kt < NT - 2)       wait_vm<2 * LPS>();
    else if (kt == NT - 2) wait_vm<LPS>();
    else                   wait_vm<0>();
    __builtin_amdgcn_s_barrier();
    __builtin_amdgcn_sched_barrier(0);

    bf16x8 af[WM], bg[WN];
#pragma unroll
    for (int i = 0; i < WM; ++i) {
      const int row = wm + i * 16 + lr;
      const int slot = lg ^ ((row >> 1) & 3);
      af[i] = *(const bf16x8*)(&As[buf][row * 32 + slot * 8]);
    }
#pragma unroll
    for (int j = 0; j < WN; ++j) {
      const int row = wn + j * 16 + lr;
      const int slot = lg ^ ((row >> 1) & 3);
      bg[j] = *(const bf16x8*)(&Bs[buf][row * 32 + slot * 8]);
    }
    asm volatile("s_waitcnt lgkmcnt(0)" ::: "memory");
    __builtin_amdgcn_sched_barrier(0);
    __builtin_amdgcn_s_barrier();

    if (kt + 3 < NT) stage(buf, (kt + 3) * 32);

#pragma unroll
    for (int i = 0; i < WM; ++i)
#pragma unroll
      for (int j = 0; j < WN; ++j)
        acc[i][j] = __builtin_amdgcn_mfma_f32_16x16x32_bf16(af[i], bg[j], acc[i][j], 0, 0, 0);

    buf = (buf == 2) ? 0 : buf + 1;
  }

  const int orow = lg * 4;
  const float* addf = (const float*)add_;
  const unsigned short* addb = (const unsigned short*)add_;
  float* outf = (float*)out_;
  unsigned short* outb = (unsigned short*)out_;
#pragma unroll
  for (int i = 0; i < WM; ++i) {
#pragma unroll
    for (int j = 0; j < WN; ++j) {
      const int n = n0 + wn + j * 16 + lr;
      if (n < N) {
#pragma unroll
        for (int r = 0; r < 4; ++r) {
          const int m = m0 + wm + i * 16 + orow + r;
          if (m < M) {
            float v = acc[i][j][r] + bias[n];
            if (HAS_ADD) v += ADD_BF16 ? bf2f(addb[(size_t)m * N + n]) : addf[(size_t)m * N + n];
            if (OUT_BF16) outb[(size_t)m * N + n] = f2bf(v);
            else          outf[(size_t)m * N + n] = v;
          }
        }
      }
    }
  }
}

// ---------------- DIRECT MFMA GEMM: no LDS, no barriers. B is L2-resident
// (<=1.2MB for all uses). Each wave owns 16 rows x WN2*16 cols; A fragments
// stream from HBM (16 rows x 64B = full lines per k-step), B fragments hit L2.
// Latency hidden by TLP + unrolled independent loads. M must be multiple of 64.
template <int WN2, int JCH, bool HAS_ADD, bool ADD_BF16, bool OUT_BF16>
__global__ __launch_bounds__(256) void gemm_direct(const unsigned short* __restrict__ A,
                                                   const unsigned short* __restrict__ Bt,
                                                   const float* __restrict__ bias,
                                                   const void* __restrict__ add_,
                                                   void* __restrict__ out_,
                                                   int M, int N, int K, int nn) {
  const int t = threadIdx.x;
  const int wave = t >> 6, lane = t & 63;
  const int lr = lane & 15, lg = lane >> 4;

  const int nwg = gridDim.x;
  const int qq = nwg >> 3, rr = nwg & 7;
  const int xcd = blockIdx.x & 7, pos = blockIdx.x >> 3;
  const int swz = ((xcd < rr) ? xcd * (qq + 1) : rr * (qq + 1) + (xcd - rr) * qq) + pos;
  const int m0 = (swz / nn) * 64 + wave * 16;
  const int n0 = (swz % nn) * (WN2 * 16);

  const unsigned short* ap = A + (size_t)(m0 + lr) * K + lg * 8;
  f32x4 acc[WN2] = {};

#pragma unroll 2
  for (int k0 = 0; k0 < K; k0 += 32) {
    bf16x8 af = *(const bf16x8*)(ap + k0);
#pragma unroll
    for (int jc = 0; jc < WN2 / JCH; ++jc) {
      bf16x8 bg[JCH];
#pragma unroll
      for (int u = 0; u < JCH; ++u) {
        const int j = jc * JCH + u;
        bg[u] = *(const bf16x8*)(Bt + (size_t)(n0 + j * 16 + lr) * K + k0 + lg * 8);
      }
#pragma unroll
      for (int u = 0; u < JCH; ++u)
        acc[jc * JCH + u] =
            __builtin_amdgcn_mfma_f32_16x16x32_bf16(af, bg[u], acc[jc * JCH + u], 0, 0, 0);
    }
  }

  const float* addf = (const float*)add_;
  const unsigned short* addb = (const unsigned short*)add_;
  float* outf = (float*)out_;
  unsigned short* outb = (unsigned short*)out_;
#pragma unroll
  for (int j = 0; j < WN2; ++j) {
    const int n = n0 + j * 16 + lr;
    if (n < N) {
#pragma unroll
      for (int r = 0; r < 4; ++r) {
        const int m = m0 + lg * 4 + r;
        float v = acc[j][r] + bias[n];
        if (HAS_ADD) v += ADD_BF16 ? bf2f(addb[(size_t)m * N + n]) : addf[(size_t)m * N + n];
        if (OUT_BF16) outb[(size_t)m * N + n] = f2bf(v);
        else          outf[(size_t)m * N + n] = v;
      }
    }
  }
}

// ---------------- deformable sampling: softmax(attw) + bilinear gather + NP-sum
__global__ __launch_bounds__(192) void deform_attn(const float* __restrict__ soaw,
                                                   const float* __restrict__ rp,
                                                   const float* __restrict__ value,
                                                   unsigned short* __restrict__ attn) {
  const int row = blockIdx.x;  // b*LQT + q
  const int b = row / LQT;
  const int t = threadIdx.x;
  const int h = t >> 5;
  const int l = t & 31;
  const float* sa = soaw + (size_t)row * 128;
  const float bx = rp[(size_t)row * 2 + 0] * (float)WW - 0.5f;
  const float by = rp[(size_t)row * 2 + 1] * (float)HH - 0.5f;

  float lg0 = sa[48 + h * 4 + 0], lg1 = sa[48 + h * 4 + 1];
  float lg2 = sa[48 + h * 4 + 2], lg3 = sa[48 + h * 4 + 3];
  float mx = fmaxf(fmaxf(lg0, lg1), fmaxf(lg2, lg3));
  float e0 = expf(lg0 - mx), e1 = expf(lg1 - mx), e2 = expf(lg2 - mx), e3 = expf(lg3 - mx);
  float inv = 1.0f / (e0 + e1 + e2 + e3);
  float awp[4] = {e0 * inv, e1 * inv, e2 * inv, e3 * inv};

  const float* vb = value + (size_t)b * LINT * DIMC + h * DHD + l * 4;
  float ax = 0.f, ay = 0.f, az = 0.f, aw = 0.f;
#pragma unroll
  for (int p = 0; p < 4; ++p) {
    float fx = bx + sa[h * 8 + p * 2 + 0];
    float fy = by + sa[h * 8 + p * 2 + 1];
    float x0f = floorf(fx), y0f = floorf(fy);
    float wx = fx - x0f, wy = fy - y0f;
    int x0 = (int)x0f, y0 = (int)y0f;
#pragma unroll
    for (int dy = 0; dy < 2; ++dy) {
#pragma unroll
      for (int dx = 0; dx < 2; ++dx) {
        int xi = x0 + dx, yi = y0 + dy;
        float w = (dy ? wy : 1.f - wy) * (dx ? wx : 1.f - wx) * awp[p];
        if (xi < 0 || xi >= WW || yi < 0 || yi >= HH) w = 0.f;
        int xc = min(max(xi, 0), WW - 1), yc = min(max(yi, 0), HH - 1);
        const float4 g = *(const float4*)(vb + (size_t)(yc * WW + xc) * DIMC);
        ax += w * g.x; ay += w * g.y; az += w * g.z; aw += w * g.w;
      }
    }
  }
  unsigned short* op = attn + (size_t)row * DIMC + h * DHD + l * 4;
  ushort4 ov;
  ov.x = f2bf(ax); ov.y = f2bf(ay); ov.z = f2bf(az); ov.w = f2bf(aw);
  *(ushort4*)op = ov;
}

// ---------------- depthwise 3x3 conv (3 image scales) + exact GELU, bf16 in/out
__global__ __launch_bounds__(192) void dwconv_gelu(const unsigned short* __restrict__ h1,
                                                   const float* __restrict__ dwW,
                                                   const float* __restrict__ dwb,
                                                   unsigned short* __restrict__ out) {
  const int blk = blockIdx.x;  // b*LQT + q
  const int b = blk / LQT;
  const int q = blk % LQT;
  int base, Wi, Hi;
  if (q < 9216)       { base = 0;     Wi = 96; Hi = 96; }
  else if (q < 11520) { base = 9216;  Wi = 48; Hi = 48; }
  else                { base = 11520; Wi = 24; Hi = 24; }
  const int loc = q - base;
  const int y = loc / Wi, x = loc % Wi;
  const int c = threadIdx.x;
  const unsigned short* src = h1 + ((size_t)b * LQT + base) * HIDC + c;
  float acc = dwb[c];
#pragma unroll
  for (int dy = -1; dy <= 1; ++dy) {
    int yy = y + dy;
    if (yy < 0 || yy >= Hi) continue;
#pragma unroll
    for (int dx = -1; dx <= 1; ++dx) {
      int xx = x + dx;
      if (xx < 0 || xx >= Wi) continue;
      acc += dwW[c * 9 + (dy + 1) * 3 + (dx + 1)] * bf2f(src[(size_t)(yy * Wi + xx) * HIDC]);
    }
  }
  float g = 0.5f * acc * (1.0f + erff(acc * 0.70710678118654752f));
  out[(size_t)blk * HIDC + c] = f2bf(g);
}

// ---------------- launch
extern "C" void kernel_launch(void* const* d_in, const int* in_sizes, int n_in,
                              void* d_out, int out_size, void* d_ws, size_t ws_size,
                              hipStream_t stream) {
  const float* query = (const float*)d_in[0];
  const float* rp    = (const float*)d_in[1];
  const float* feat  = (const float*)d_in[2];
  const float* qn_g  = (const float*)d_in[7];
  const float* qn_b  = (const float*)d_in[8];
  const float* fn_g  = (const float*)d_in[9];
  const float* fn_b  = (const float*)d_in[10];
  const float* mn_g  = (const float*)d_in[11];
  const float* mn_b  = (const float*)d_in[12];
  const float* vW    = (const float*)d_in[13];
  const float* vb    = (const float*)d_in[14];
  const float* soW   = (const float*)d_in[15];
  const float* sob   = (const float*)d_in[16];
  const float* awW   = (const float*)d_in[17];
  const float* awb   = (const float*)d_in[18];
  const float* opW   = (const float*)d_in[19];
  const float* opb   = (const float*)d_in[20];
  const float* fc1W  = (const float*)d_in[21];
  const float* fc1b  = (const float*)d_in[22];
  const float* dwW   = (const float*)d_in[23];
  const float* dwb   = (const float*)d_in[24];
  const float* fc2W  = (const float*)d_in[25];
  const float* fc2b  = (const float*)d_in[26];
  float* out = (float*)d_out;
  (void)in_sizes; (void)n_in; (void)out_size; (void)ws_size;

  char* ws = (char*)d_ws;
  size_t off = 0;
  auto alloc = [&](size_t bytes) -> void* {
    off = (off + 255) & ~(size_t)255;
    void* p = ws + off;
    off += bytes;
    return p;
  };

  const int MQ = NB * LQT;    // 24192 (multiple of 64)
  const int MF = NB * LINT;   // 4608

  unsigned short* vWt    = (unsigned short*)alloc((size_t)768 * 768 * 2);
  unsigned short* opWt   = (unsigned short*)alloc((size_t)768 * 768 * 2);
  unsigned short* soawWt = (unsigned short*)alloc((size_t)128 * 768 * 2);
  unsigned short* fc1Wt  = (unsigned short*)alloc((size_t)192 * 768 * 2);
  unsigned short* fc2Wt  = (unsigned short*)alloc((size_t)768 * 192 * 2);
  float*          soawb  = (float*)alloc(128 * 4);
  unsigned short* f_ln   = (unsigned short*)alloc((size_t)MF * DIMC * 2);
  unsigned short* q_ln   = (unsigned short*)alloc((size_t)MQ * DIMC * 2);  // reused as ln(x)
  float*          value  = (float*)alloc((size_t)MF * DIMC * 4);
  float*          soaw   = (float*)alloc((size_t)MQ * 128 * 4);            // reused as conv out (bf16)
  unsigned short* attnb  = (unsigned short*)alloc((size_t)MQ * DIMC * 2);  // reused as h1 (bf16)
  unsigned short* xbuf   = (unsigned short*)alloc((size_t)MQ * DIMC * 2);  // x residual in bf16

  unsigned short* h1b = attnb;                  // fc1 output (bf16), after attnb consumed
  unsigned short* coutb = (unsigned short*)soaw;
  unsigned short* lnx = q_ln;

  // weight packing (tiny)
  pack_wt<<<dim3((768 * 768 + 255) / 256), dim3(256), 0, stream>>>(vW, vWt, 768, 768, 768);
  pack_wt<<<dim3((768 * 768 + 255) / 256), dim3(256), 0, stream>>>(opW, opWt, 768, 768, 768);
  pack_wt<<<dim3((192 * 768 + 255) / 256), dim3(256), 0, stream>>>(fc1W, fc1Wt, 768, 192, 192);
  pack_wt<<<dim3((768 * 192 + 255) / 256), dim3(256), 0, stream>>>(fc2W, fc2Wt, 192, 768, 768);
  pack_soaw<<<dim3((128 * 768 + 255) / 256), dim3(256), 0, stream>>>(soW, awW, sob, awb, soawWt, soawb);

  // LayerNorms (fp32 in)
  ln_to_bf16<false><<<dim3(MF), dim3(256), 0, stream>>>(feat, fn_g, fn_b, f_ln);
  ln_to_bf16<false><<<dim3(MQ), dim3(256), 0, stream>>>(query, qn_g, qn_b, q_ln);

  // value projection (LDS pipeline; M small): [4608,768] = f_ln @ vW + vb
  gemm_bt<2, 4, false, false, false><<<dim3((MF / 64) * 6), dim3(256), 0, stream>>>(
      f_ln, vWt, vb, nullptr, value, MF, 768, 768, 6);

  // sampling offsets + attn logits (direct; N=128, B=192KB L2-resident)
  gemm_direct<8, 8, false, false, false><<<dim3(MQ / 64), dim3(256), 0, stream>>>(
      q_ln, soawWt, soawb, nullptr, soaw, MQ, 128, 768, 1);

  // deformable bilinear sampling -> attn operand (bf16)
  deform_attn<<<dim3(MQ), dim3(192), 0, stream>>>(soaw, rp, value, attnb);

  // output projection + residual (direct; B=1.1MB L2): x = attn @ opW + opb + query
  gemm_direct<16, 8, true, false, true><<<dim3((MQ / 64) * 3), dim3(256), 0, stream>>>(
      attnb, opWt, opb, query, xbuf, MQ, 768, 768, 3);

  // LN(x) (bf16 in)
  ln_to_bf16<true><<<dim3(MQ), dim3(256), 0, stream>>>(xbuf, mn_g, mn_b, lnx);

  // fc1 (direct; N=192, B=288KB L2): h1 = lnx @ fc1W + fc1b   (bf16 out)
  gemm_direct<12, 6, false, false, true><<<dim3(MQ / 64), dim3(256), 0, stream>>>(
      lnx, fc1Wt, fc1b, nullptr, h1b, MQ, 192, 768, 1);

  // depthwise conv (3 scales) + GELU (bf16 in/out)
  dwconv_gelu<<<dim3(MQ), dim3(192), 0, stream>>>(h1b, dwW, dwb, coutb);

  // fc2 + residual (direct; K=192, B=288KB L2): out = x + cout @ fc2W + fc2b
  gemm_direct<16, 8, true, true, false><<<dim3((MQ / 64) * 3), dim3(256), 0, stream>>>(
      coutb, fc2Wt, fc2b, xbuf, out, MQ, 768, 192, 3);
}

// Round 8
// 361.952 us; speedup vs baseline: 1.7125x; 1.7125x over previous
//
#include <hip/hip_runtime.h>

// Problem constants (fixed by the reference)
#define NB    2
#define LQT   12096      // query tokens per batch
#define LINT  2304       // feat tokens per batch (48*48)
#define DIMC  768
#define NHD   6
#define NPT   4
#define DHD   128
#define HIDC  192
#define HH    48
#define WW    48

typedef __attribute__((ext_vector_type(8))) short bf16x8;
typedef __attribute__((ext_vector_type(4))) float f32x4;

__device__ __forceinline__ unsigned short f2bf(float f) {
  unsigned int u = __builtin_bit_cast(unsigned int, f);
  u += 0x7FFFu + ((u >> 16) & 1u);   // round-to-nearest-even
  return (unsigned short)(u >> 16);
}
__device__ __forceinline__ float bf2f(unsigned short h) {
  unsigned int u = ((unsigned int)h) << 16;
  return __builtin_bit_cast(float, u);
}

// global -> LDS direct copy, 16B per lane. LDS base must be wave-uniform.
__device__ __forceinline__ void gload16(const unsigned short* g, unsigned short* l) {
  __builtin_amdgcn_global_load_lds(
      (const __attribute__((address_space(1))) unsigned int*)g,
      (__attribute__((address_space(3))) unsigned int*)l, 16, 0, 0);
}

template <int N> __device__ __forceinline__ void wait_vm() {
  if constexpr (N == 0)      asm volatile("s_waitcnt vmcnt(0)" ::: "memory");
  else if constexpr (N == 3) asm volatile("s_waitcnt vmcnt(3)" ::: "memory");
  else if constexpr (N == 6) asm volatile("s_waitcnt vmcnt(6)" ::: "memory");
  else if constexpr (N == 8) asm volatile("s_waitcnt vmcnt(8)" ::: "memory");
}

// ---------------- weight packing: transpose [K][N]->bf16 [rows>=N][K], pad rows with 0
__global__ __launch_bounds__(256) void pack_wt(const float* __restrict__ src,
                                               unsigned short* __restrict__ dst,
                                               int K, int N, int rows) {
  size_t i = (size_t)blockIdx.x * 256 + threadIdx.x;
  if (i >= (size_t)rows * K) return;
  int n = (int)(i / K), k = (int)(i % K);
  float v = (n < N) ? src[(size_t)k * N + n] : 0.f;
  dst[i] = f2bf(v);
}

// fused sampling-offset (48 cols) + attn-weight (24 cols) weight pack into [128][768]
__global__ __launch_bounds__(256) void pack_soaw(const float* __restrict__ soW,
                                                 const float* __restrict__ awW,
                                                 const float* __restrict__ sob,
                                                 const float* __restrict__ awb,
                                                 unsigned short* __restrict__ dst,
                                                 float* __restrict__ bdst) {
  size_t i = (size_t)blockIdx.x * 256 + threadIdx.x;
  if (i < 128) bdst[i] = (i < 48) ? sob[i] : (i < 72 ? awb[i - 48] : 0.f);
  if (i >= (size_t)128 * DIMC) return;
  int n = (int)(i / DIMC), k = (int)(i % DIMC);
  float v = (n < 48) ? soW[(size_t)k * 48 + n]
                     : (n < 72 ? awW[(size_t)k * 24 + (n - 48)] : 0.f);
  dst[i] = f2bf(v);
}

// ---------------- LayerNorm (eps=1e-6), templated input dtype, -> bf16
template <bool IN_BF16>
__global__ __launch_bounds__(256) void ln_to_bf16(const void* __restrict__ in_,
                                                  const float* __restrict__ gamma,
                                                  const float* __restrict__ beta,
                                                  unsigned short* __restrict__ out) {
  const int row = blockIdx.x;
  const int t = threadIdx.x;
  float v0, v1, v2;
  if (IN_BF16) {
    const unsigned short* x = (const unsigned short*)in_ + (size_t)row * DIMC;
    v0 = bf2f(x[t]); v1 = bf2f(x[t + 256]); v2 = bf2f(x[t + 512]);
  } else {
    const float* x = (const float*)in_ + (size_t)row * DIMC;
    v0 = x[t]; v1 = x[t + 256]; v2 = x[t + 512];
  }
  float s = v0 + v1 + v2;
  float s2 = v0 * v0 + v1 * v1 + v2 * v2;
#pragma unroll
  for (int o = 32; o > 0; o >>= 1) {
    s += __shfl_down(s, o);
    s2 += __shfl_down(s2, o);
  }
  __shared__ float red[8];
  const int wave = t >> 6, lane = t & 63;
  if (lane == 0) { red[wave] = s; red[wave + 4] = s2; }
  __syncthreads();
  float S = red[0] + red[1] + red[2] + red[3];
  float S2 = red[4] + red[5] + red[6] + red[7];
  float mean = S * (1.0f / DIMC);
  float var = S2 * (1.0f / DIMC) - mean * mean;
  float inv = rsqrtf(var + 1e-6f);
  unsigned short* o0 = out + (size_t)row * DIMC;
  o0[t]       = f2bf((v0 - mean) * inv * gamma[t]       + beta[t]);
  o0[t + 256] = f2bf((v1 - mean) * inv * gamma[t + 256] + beta[t + 256]);
  o0[t + 512] = f2bf((v2 - mean) * inv * gamma[t + 512] + beta[t + 512]);
}

// ---------------- LDS-pipelined MFMA GEMM (R5 structure; v-proj, soaw, fc1)
// 4 waves (2x2), BK=32, triple-buffered counted-vmcnt pipeline.
template <int WM, int WN, bool HAS_ADD, bool ADD_BF16, bool OUT_BF16>
__global__ __launch_bounds__(256) void gemm_bt(const unsigned short* __restrict__ A,
                                               const unsigned short* __restrict__ Bt,
                                               const float* __restrict__ bias,
                                               const void* __restrict__ add_,
                                               void* __restrict__ out_,
                                               int M, int N, int K, int nn) {
  constexpr int BM = 2 * WM * 16;
  constexpr int BN = 2 * WN * 16;
  constexpr int LPS = (BM + BN) / 64;
  constexpr int CA = BM * 4;
  __shared__ unsigned short As[3][BM * 32];
  __shared__ unsigned short Bs[3][BN * 32];
  const int t = threadIdx.x;
  const int wave = t >> 6, lane = t & 63;

  const int nwg = gridDim.x;
  const int qq = nwg >> 3, rr = nwg & 7;
  const int xcd = blockIdx.x & 7, pos = blockIdx.x >> 3;
  const int swz = ((xcd < rr) ? xcd * (qq + 1) : rr * (qq + 1) + (xcd - rr) * qq) + pos;
  const int m0 = (swz / nn) * BM;
  const int n0 = (swz % nn) * BN;

  const int wm = (wave >> 1) * (WM * 16), wn = (wave & 1) * (WN * 16);
  const int lr = lane & 15;
  const int lg = lane >> 4;

  auto stage = [&](int buf, int k0) {
#pragma unroll
    for (int i = 0; i < LPS; ++i) {
      const int c = t + i * 256;
      if (c < CA) {
        const int row = c >> 2, slot = c & 3;
        const int ca = slot ^ ((row >> 1) & 3);
        gload16(A + (size_t)(m0 + row) * K + k0 + ca * 8, &As[buf][c * 8]);
      } else {
        const int c2 = c - CA, row = c2 >> 2, slot = c2 & 3;
        const int ca = slot ^ ((row >> 1) & 3);
        gload16(Bt + (size_t)(n0 + row) * K + k0 + ca * 8, &Bs[buf][c2 * 8]);
      }
    }
  };

  f32x4 acc[WM][WN] = {};
  const int NT = K >> 5;

  stage(0, 0);
  stage(1, 32);
  stage(2, 64);

  int buf = 0;
  for (int kt = 0; kt < NT; ++kt) {
    if (kt < NT - 2)       wait_vm<2 * LPS>();
    else if (kt == NT - 2) wait_vm<LPS>();
    else                   wait_vm<0>();
    __builtin_amdgcn_s_barrier();
    __builtin_amdgcn_sched_barrier(0);

    bf16x8 af[WM], bg[WN];
#pragma unroll
    for (int i = 0; i < WM; ++i) {
      const int row = wm + i * 16 + lr;
      const int slot = lg ^ ((row >> 1) & 3);
      af[i] = *(const bf16x8*)(&As[buf][row * 32 + slot * 8]);
    }
#pragma unroll
    for (int j = 0; j < WN; ++j) {
      const int row = wn + j * 16 + lr;
      const int slot = lg ^ ((row >> 1) & 3);
      bg[j] = *(const bf16x8*)(&Bs[buf][row * 32 + slot * 8]);
    }
    asm volatile("s_waitcnt lgkmcnt(0)" ::: "memory");
    __builtin_amdgcn_sched_barrier(0);
    __builtin_amdgcn_s_barrier();

    if (kt + 3 < NT) stage(buf, (kt + 3) * 32);

#pragma unroll
    for (int i = 0; i < WM; ++i)
#pragma unroll
      for (int j = 0; j < WN; ++j)
        acc[i][j] = __builtin_amdgcn_mfma_f32_16x16x32_bf16(af[i], bg[j], acc[i][j], 0, 0, 0);

    buf = (buf == 2) ? 0 : buf + 1;
  }

  const int orow = lg * 4;
  const float* addf = (const float*)add_;
  const unsigned short* addb = (const unsigned short*)add_;
  float* outf = (float*)out_;
  unsigned short* outb = (unsigned short*)out_;
#pragma unroll
  for (int i = 0; i < WM; ++i) {
#pragma unroll
    for (int j = 0; j < WN; ++j) {
      const int n = n0 + wn + j * 16 + lr;
      if (n < N) {
#pragma unroll
        for (int r = 0; r < 4; ++r) {
          const int m = m0 + wm + i * 16 + orow + r;
          if (m < M) {
            float v = acc[i][j][r] + bias[n];
            if (HAS_ADD) v += ADD_BF16 ? bf2f(addb[(size_t)m * N + n]) : addf[(size_t)m * N + n];
            if (OUT_BF16) outb[(size_t)m * N + n] = f2bf(v);
            else          outf[(size_t)m * N + n] = v;
          }
        }
      }
    }
  }
}

// ---------------- 8-wave MFMA GEMM for the fat-M GEMMs (out-proj, fc2).
// BM=256, BN=128, BK=32, 512 threads = 8 waves (4m x 2n), wave-tile 64x64.
// acc = 64 AGPR/wave -> 2 blocks/CU (16 waves/CU). Double-buffered LDS (48KB),
// ONE barrier per K-step: vmcnt(0) -> barrier -> issue next tile -> ds_read ->
// lgkmcnt(0)+sched_barrier -> setprio-wrapped MFMA. Overwrite of buf p^1 is
// safe: every wave's reads of it retired (lgkmcnt) before it reached this
// barrier. Slot-XOR swizzle on both sides (rule #21). M padded to 256 by
// caller's buffers; epilogue guards m < M. N must be a multiple of 128.
template <bool HAS_ADD, bool ADD_BF16, bool OUT_BF16>
__global__ __launch_bounds__(512, 4) void gemm8(const unsigned short* __restrict__ A,
                                                const unsigned short* __restrict__ Bt,
                                                const float* __restrict__ bias,
                                                const void* __restrict__ add_,
                                                void* __restrict__ out_,
                                                int M, int N, int K, int nn) {
  __shared__ unsigned short As[2][256 * 32];
  __shared__ unsigned short Bs[2][128 * 32];
  const int t = threadIdx.x;
  const int wave = t >> 6, lane = t & 63;

  const int nwg = gridDim.x;
  const int qq = nwg >> 3, rr = nwg & 7;
  const int xcd = blockIdx.x & 7, pos = blockIdx.x >> 3;
  const int swz = ((xcd < rr) ? xcd * (qq + 1) : rr * (qq + 1) + (xcd - rr) * qq) + pos;
  const int m0 = (swz / nn) * 256;
  const int n0 = (swz % nn) * 128;

  const int wm = (wave >> 1) * 64;   // 4 m-waves
  const int wn = (wave & 1) * 64;    // 2 n-waves
  const int lr = lane & 15;
  const int lg = lane >> 4;

  // staging: thread t owns A rows (t>>2) and (t>>2)+128, B row (t>>2); slot t&3.
  const int srow = t >> 2, sslot = t & 3;
  const int sca = sslot ^ ((srow >> 1) & 3);      // same xor for row+128 (128>>1 ≡ 0 mod 4)
  const unsigned short* pa = A + (size_t)(m0 + srow) * K + sca * 8;
  const unsigned short* pb = Bt + (size_t)(n0 + srow) * K + sca * 8;
  const size_t arow2 = (size_t)128 * K;

  auto stage = [&](int buf, int k0) {
    gload16(pa + k0, &As[buf][t * 8]);
    gload16(pa + arow2 + k0, &As[buf][(t + 512) * 8]);
    gload16(pb + k0, &Bs[buf][t * 8]);
  };

  f32x4 acc[4][4] = {};
  const int NT = K >> 5;

  stage(0, 0);

  for (int kt = 0; kt < NT; ++kt) {
    const int p = kt & 1;
    asm volatile("s_waitcnt vmcnt(0)" ::: "memory");   // tile kt's 3 loads landed
    __builtin_amdgcn_s_barrier();                      // visible to all waves
    __builtin_amdgcn_sched_barrier(0);

    if (kt + 1 < NT) stage(p ^ 1, (kt + 1) * 32);      // fly over ds_read + MFMA

    bf16x8 af[4], bg[4];
#pragma unroll
    for (int i = 0; i < 4; ++i) {
      const int row = wm + i * 16 + lr;
      const int slot = lg ^ ((row >> 1) & 3);
      af[i] = *(const bf16x8*)(&As[p][row * 32 + slot * 8]);
    }
#pragma unroll
    for (int j = 0; j < 4; ++j) {
      const int row = wn + j * 16 + lr;
      const int slot = lg ^ ((row >> 1) & 3);
      bg[j] = *(const bf16x8*)(&Bs[p][row * 32 + slot * 8]);
    }
    asm volatile("s_waitcnt lgkmcnt(0)" ::: "memory");
    __builtin_amdgcn_sched_barrier(0);                 // rule #18

    __builtin_amdgcn_s_setprio(1);
#pragma unroll
    for (int i = 0; i < 4; ++i)
#pragma unroll
      for (int j = 0; j < 4; ++j)
        acc[i][j] = __builtin_amdgcn_mfma_f32_16x16x32_bf16(af[i], bg[j], acc[i][j], 0, 0, 0);
    __builtin_amdgcn_s_setprio(0);
  }

  const int orow = lg * 4;
  const float* addf = (const float*)add_;
  const unsigned short* addb = (const unsigned short*)add_;
  float* outf = (float*)out_;
  unsigned short* outb = (unsigned short*)out_;
#pragma unroll
  for (int i = 0; i < 4; ++i) {
#pragma unroll
    for (int j = 0; j < 4; ++j) {
      const int n = n0 + wn + j * 16 + lr;
#pragma unroll
      for (int r = 0; r < 4; ++r) {
        const int m = m0 + wm + i * 16 + orow + r;
        if (m < M) {
          float v = acc[i][j][r] + bias[n];
          if (HAS_ADD) v += ADD_BF16 ? bf2f(addb[(size_t)m * N + n]) : addf[(size_t)m * N + n];
          if (OUT_BF16) outb[(size_t)m * N + n] = f2bf(v);
          else          outf[(size_t)m * N + n] = v;
        }
      }
    }
  }
}

// ---------------- deformable sampling: softmax(attw) + bilinear gather + NP-sum
__global__ __launch_bounds__(192) void deform_attn(const float* __restrict__ soaw,
                                                   const float* __restrict__ rp,
                                                   const float* __restrict__ value,
                                                   unsigned short* __restrict__ attn) {
  const int row = blockIdx.x;  // b*LQT + q
  const int b = row / LQT;
  const int t = threadIdx.x;
  const int h = t >> 5;
  const int l = t & 31;
  const float* sa = soaw + (size_t)row * 128;
  const float bx = rp[(size_t)row * 2 + 0] * (float)WW - 0.5f;
  const float by = rp[(size_t)row * 2 + 1] * (float)HH - 0.5f;

  float lg0 = sa[48 + h * 4 + 0], lg1 = sa[48 + h * 4 + 1];
  float lg2 = sa[48 + h * 4 + 2], lg3 = sa[48 + h * 4 + 3];
  float mx = fmaxf(fmaxf(lg0, lg1), fmaxf(lg2, lg3));
  float e0 = expf(lg0 - mx), e1 = expf(lg1 - mx), e2 = expf(lg2 - mx), e3 = expf(lg3 - mx);
  float inv = 1.0f / (e0 + e1 + e2 + e3);
  float awp[4] = {e0 * inv, e1 * inv, e2 * inv, e3 * inv};

  const float* vb = value + (size_t)b * LINT * DIMC + h * DHD + l * 4;
  float ax = 0.f, ay = 0.f, az = 0.f, aw = 0.f;
#pragma unroll
  for (int p = 0; p < 4; ++p) {
    float fx = bx + sa[h * 8 + p * 2 + 0];
    float fy = by + sa[h * 8 + p * 2 + 1];
    float x0f = floorf(fx), y0f = floorf(fy);
    float wx = fx - x0f, wy = fy - y0f;
    int x0 = (int)x0f, y0 = (int)y0f;
#pragma unroll
    for (int dy = 0; dy < 2; ++dy) {
#pragma unroll
      for (int dx = 0; dx < 2; ++dx) {
        int xi = x0 + dx, yi = y0 + dy;
        float w = (dy ? wy : 1.f - wy) * (dx ? wx : 1.f - wx) * awp[p];
        if (xi < 0 || xi >= WW || yi < 0 || yi >= HH) w = 0.f;
        int xc = min(max(xi, 0), WW - 1), yc = min(max(yi, 0), HH - 1);
        const float4 g = *(const float4*)(vb + (size_t)(yc * WW + xc) * DIMC);
        ax += w * g.x; ay += w * g.y; az += w * g.z; aw += w * g.w;
      }
    }
  }
  unsigned short* op = attn + (size_t)row * DIMC + h * DHD + l * 4;
  ushort4 ov;
  ov.x = f2bf(ax); ov.y = f2bf(ay); ov.z = f2bf(az); ov.w = f2bf(aw);
  *(ushort4*)op = ov;
}

// ---------------- depthwise 3x3 conv (3 image scales) + exact GELU, bf16 in/out
__global__ __launch_bounds__(192) void dwconv_gelu(const unsigned short* __restrict__ h1,
                                                   const float* __restrict__ dwW,
                                                   const float* __restrict__ dwb,
                                                   unsigned short* __restrict__ out) {
  const int blk = blockIdx.x;  // b*LQT + q
  const int b = blk / LQT;
  const int q = blk % LQT;
  int base, Wi, Hi;
  if (q < 9216)       { base = 0;     Wi = 96; Hi = 96; }
  else if (q < 11520) { base = 9216;  Wi = 48; Hi = 48; }
  else                { base = 11520; Wi = 24; Hi = 24; }
  const int loc = q - base;
  const int y = loc / Wi, x = loc % Wi;
  const int c = threadIdx.x;
  const unsigned short* src = h1 + ((size_t)b * LQT + base) * HIDC + c;
  float acc = dwb[c];
#pragma unroll
  for (int dy = -1; dy <= 1; ++dy) {
    int yy = y + dy;
    if (yy < 0 || yy >= Hi) continue;
#pragma unroll
    for (int dx = -1; dx <= 1; ++dx) {
      int xx = x + dx;
      if (xx < 0 || xx >= Wi) continue;
      acc += dwW[c * 9 + (dy + 1) * 3 + (dx + 1)] * bf2f(src[(size_t)(yy * Wi + xx) * HIDC]);
    }
  }
  float g = 0.5f * acc * (1.0f + erff(acc * 0.70710678118654752f));
  out[(size_t)blk * HIDC + c] = f2bf(g);
}

// ---------------- launch
extern "C" void kernel_launch(void* const* d_in, const int* in_sizes, int n_in,
                              void* d_out, int out_size, void* d_ws, size_t ws_size,
                              hipStream_t stream) {
  const float* query = (const float*)d_in[0];
  const float* rp    = (const float*)d_in[1];
  const float* feat  = (const float*)d_in[2];
  const float* qn_g  = (const float*)d_in[7];
  const float* qn_b  = (const float*)d_in[8];
  const float* fn_g  = (const float*)d_in[9];
  const float* fn_b  = (const float*)d_in[10];
  const float* mn_g  = (const float*)d_in[11];
  const float* mn_b  = (const float*)d_in[12];
  const float* vW    = (const float*)d_in[13];
  const float* vb    = (const float*)d_in[14];
  const float* soW   = (const float*)d_in[15];
  const float* sob   = (const float*)d_in[16];
  const float* awW   = (const float*)d_in[17];
  const float* awb   = (const float*)d_in[18];
  const float* opW   = (const float*)d_in[19];
  const float* opb   = (const float*)d_in[20];
  const float* fc1W  = (const float*)d_in[21];
  const float* fc1b  = (const float*)d_in[22];
  const float* dwW   = (const float*)d_in[23];
  const float* dwb   = (const float*)d_in[24];
  const float* fc2W  = (const float*)d_in[25];
  const float* fc2b  = (const float*)d_in[26];
  float* out = (float*)d_out;
  (void)in_sizes; (void)n_in; (void)out_size; (void)ws_size;

  char* ws = (char*)d_ws;
  size_t off = 0;
  auto alloc = [&](size_t bytes) -> void* {
    off = (off + 255) & ~(size_t)255;
    void* p = ws + off;
    off += bytes;
    return p;
  };

  const int MQ = NB * LQT;    // 24192
  const int MQP = 24320;      // MQ rounded up to 256 (pad rows for BM=256 staging)
  const int MF = NB * LINT;   // 4608

  unsigned short* vWt    = (unsigned short*)alloc((size_t)768 * 768 * 2);
  unsigned short* opWt   = (unsigned short*)alloc((size_t)768 * 768 * 2);
  unsigned short* soawWt = (unsigned short*)alloc((size_t)128 * 768 * 2);
  unsigned short* fc1Wt  = (unsigned short*)alloc((size_t)192 * 768 * 2);
  unsigned short* fc2Wt  = (unsigned short*)alloc((size_t)768 * 192 * 2);
  float*          soawb  = (float*)alloc(128 * 4);
  unsigned short* f_ln   = (unsigned short*)alloc((size_t)MF * DIMC * 2);
  unsigned short* q_ln   = (unsigned short*)alloc((size_t)MQ * DIMC * 2);  // reused as ln(x)
  float*          value  = (float*)alloc((size_t)MF * DIMC * 4);
  float*          soaw   = (float*)alloc((size_t)MQP * 128 * 4);           // reused as conv out (bf16, padded rows)
  unsigned short* attnb  = (unsigned short*)alloc((size_t)MQP * DIMC * 2); // padded rows; reused as h1 (bf16)
  unsigned short* xbuf   = (unsigned short*)alloc((size_t)MQ * DIMC * 2);  // x residual in bf16

  unsigned short* h1b = attnb;                  // fc1 output (bf16), after attnb consumed
  unsigned short* coutb = (unsigned short*)soaw; // MQP*192*2 = 9.3MB < 12.4MB
  unsigned short* lnx = q_ln;

  // weight packing (tiny)
  pack_wt<<<dim3((768 * 768 + 255) / 256), dim3(256), 0, stream>>>(vW, vWt, 768, 768, 768);
  pack_wt<<<dim3((768 * 768 + 255) / 256), dim3(256), 0, stream>>>(opW, opWt, 768, 768, 768);
  pack_wt<<<dim3((192 * 768 + 255) / 256), dim3(256), 0, stream>>>(fc1W, fc1Wt, 768, 192, 192);
  pack_wt<<<dim3((768 * 192 + 255) / 256), dim3(256), 0, stream>>>(fc2W, fc2Wt, 192, 768, 768);
  pack_soaw<<<dim3((128 * 768 + 255) / 256), dim3(256), 0, stream>>>(soW, awW, sob, awb, soawWt, soawb);

  // LayerNorms (fp32 in)
  ln_to_bf16<false><<<dim3(MF), dim3(256), 0, stream>>>(feat, fn_g, fn_b, f_ln);
  ln_to_bf16<false><<<dim3(MQ), dim3(256), 0, stream>>>(query, qn_g, qn_b, q_ln);

  // value projection (R5 pipeline): [4608,768] = f_ln @ vW + vb
  gemm_bt<2, 4, false, false, false><<<dim3((MF / 64) * 6), dim3(256), 0, stream>>>(
      f_ln, vWt, vb, nullptr, value, MF, 768, 768, 6);

  // sampling offsets + attn logits (R5 pipeline; N=128 padded)
  gemm_bt<2, 4, false, false, false><<<dim3(MQ / 64), dim3(256), 0, stream>>>(
      q_ln, soawWt, soawb, nullptr, soaw, MQ, 128, 768, 1);

  // deformable bilinear sampling -> attn operand (bf16)
  deform_attn<<<dim3(MQ), dim3(192), 0, stream>>>(soaw, rp, value, attnb);

  // output projection + residual (8-wave): x = attn @ opW + opb + query (bf16 out)
  gemm8<true, false, true><<<dim3((MQP / 256) * 6), dim3(512), 0, stream>>>(
      attnb, opWt, opb, query, xbuf, MQ, 768, 768, 6);

  // LN(x) (bf16 in)
  ln_to_bf16<true><<<dim3(MQ), dim3(256), 0, stream>>>(xbuf, mn_g, mn_b, lnx);

  // fc1 (R5 pipeline): h1 = lnx @ fc1W + fc1b  (bf16 out)
  gemm_bt<4, 2, false, false, true><<<dim3((MQ / 128) * 3), dim3(256), 0, stream>>>(
      lnx, fc1Wt, fc1b, nullptr, h1b, MQ, 192, 768, 3);

  // depthwise conv (3 scales) + GELU (bf16 in/out)
  dwconv_gelu<<<dim3(MQ), dim3(192), 0, stream>>>(h1b, dwW, dwb, coutb);

  // fc2 + residual (8-wave): out = x + cout @ fc2W + fc2b
  gemm8<true, true, false><<<dim3((MQP / 256) * 6), dim3(512), 0, stream>>>(
      coutb, fc2Wt, fc2b, xbuf, out, MQ, 768, 192, 6);
}